// Round 4
// baseline (345.607 us; speedup 1.0000x reference)
//
#include <hip/hip_runtime.h>

// VQ codebook: z_e [32,64,64,64] f32 (B,C,W,H), emb [1024,64] f32.
// Outputs concat: quantized [32,64,64,64] f32, indices [131072] (as f32), vq_loss [1] f32.
//
// R4: scan reads emb from LDS-staged tiles instead of SGPRs. SMEM returns
// out-of-order -> lgkmcnt(0) full drain per k (R3: VALUBusy 47%, serial
// load->drain->FMA). DS returns in-order -> counted lgkmcnt waits -> the
// compiler pipelines e-row ds_read_b128 (wave-uniform broadcast, conflict-
// free) under the FMA stream. Inner-loop arithmetic bit-identical to R1/R3
// (absmax 0.0): same fmaf chains, same fmaf(-2,dot,E[k]), same strict-<.

#define CDIM   64
#define KCODES 1024
#define NPTS   131072      // 32*64*64
#define WH     4096        // 64*64
#define CWH    262144      // 64*4096
#define SPLIT  4
#define KPER   (KCODES / SPLIT)   // 256 codes per scan block
#define KTILE  64                 // codes staged per LDS tile (16 KB)
#define NBLK   (NPTS / 256)       // 512 point-blocks

// Kernel 0: E[k] = ||emb_k||^2
__global__ __launch_bounds__(256) void vq_esq(const float* __restrict__ emb,
                                              float* __restrict__ E) {
    int k = blockIdx.x * 256 + threadIdx.x;
    if (k >= KCODES) return;
    const float4* e4 = (const float4*)(emb + k * CDIM);
    float s = 0.f;
#pragma unroll
    for (int i = 0; i < CDIM / 4; ++i) {
        float4 v = e4[i];
        s = fmaf(v.x, v.x, s);
        s = fmaf(v.y, v.y, s);
        s = fmaf(v.z, v.z, s);
        s = fmaf(v.w, v.w, s);
    }
    E[k] = s;
}

// Kernel 1: scan. blockIdx.x = point block (256 pts), blockIdx.y = k-split.
__global__ __launch_bounds__(256) void vq_scan(const float* __restrict__ z_e,
                                               const float* __restrict__ emb,
                                               const float* __restrict__ E,
                                               float* __restrict__ cand_best,
                                               int* __restrict__ cand_k) {
    const int tid = threadIdx.x;
    const int n   = blockIdx.x * 256 + tid;
    const int b   = n >> 12;
    const int wh  = n & 4095;
    const int k0  = blockIdx.y * KPER;

    __shared__ float se[KTILE * CDIM];   // 16 KB code tile
    __shared__ float sE[KTILE];          // staged ||e||^2 for the tile

    // Point's 64 channels into VGPRs. Coalesced: fixed c, consecutive lanes.
    const float* zp = z_e + (size_t)b * CWH + wh;
    float z[CDIM];
#pragma unroll
    for (int c = 0; c < CDIM; ++c) z[c] = zp[c * WH];

    float best  = 1e30f;
    int   bestk = 0;

    for (int t = 0; t < KPER / KTILE; ++t) {
        const int kbase = k0 + t * KTILE;
        __syncthreads();   // all waves done reading previous tile
        // Stage 64 codes (4096 floats): 256 threads x 4 float4, linear copy.
        {
            const float4* src = (const float4*)(emb + (size_t)kbase * CDIM);
            float4* dst = (float4*)se;
#pragma unroll
            for (int i = 0; i < 4; ++i) dst[tid + 256 * i] = src[tid + 256 * i];
            if (tid < KTILE) sE[tid] = E[kbase + tid];
        }
        __syncthreads();   // tile visible

        // Scan the tile. Broadcast ds_reads (wave-uniform addr), in-order
        // DS pipe -> compiler pipelines reads under FMAs.
        for (int kk = 0; kk < KTILE; ++kk) {
            const float* er = se + kk * CDIM;
            float d0 = 0.f, d1 = 0.f, d2 = 0.f, d3 = 0.f;
#pragma unroll
            for (int c = 0; c < CDIM; c += 4) {
                d0 = fmaf(z[c + 0], er[c + 0], d0);
                d1 = fmaf(z[c + 1], er[c + 1], d1);
                d2 = fmaf(z[c + 2], er[c + 2], d2);
                d3 = fmaf(z[c + 3], er[c + 3], d3);
            }
            float dot   = (d0 + d1) + (d2 + d3);
            float score = fmaf(-2.0f, dot, sE[kk]);
            if (score < best) { best = score; bestk = kbase + kk; }  // first-min
        }
    }

    cand_best[blockIdx.y * NPTS + n] = best;
    cand_k[blockIdx.y * NPTS + n]    = bestk;
}

// Kernel 2: merge candidates, gather winning code, write q/idx, loss partials.
__global__ __launch_bounds__(256) void vq_merge(const float* __restrict__ z_e,
                                                const float* __restrict__ emb,
                                                const float* __restrict__ cand_best,
                                                const int* __restrict__ cand_k,
                                                float* __restrict__ out_q,
                                                float* __restrict__ out_idx,
                                                float* __restrict__ partials) {
    const int tid = threadIdx.x;
    const int n   = blockIdx.x * 256 + tid;
    const int b   = n >> 12;
    const int wh  = n & 4095;

    // Ascending split order + strict < == global first-min (jnp.argmin).
    float mb = cand_best[n];
    int   mk = cand_k[n];
#pragma unroll
    for (int s = 1; s < SPLIT; ++s) {
        float v  = cand_best[s * NPTS + n];
        int   kk = cand_k[s * NPTS + n];
        if (v < mb) { mb = v; mk = kk; }
    }
    out_idx[n] = (float)mk;

    const float* eb = emb + mk * CDIM;
    const float* zp = z_e + (size_t)b * CWH + wh;
    float* qp = out_q + (size_t)b * CWH + wh;
    float lsum = 0.f;
#pragma unroll
    for (int c = 0; c < CDIM; ++c) {
        float ev = eb[c];
        qp[c * WH] = ev;
        float d = ev - zp[c * WH];
        lsum = fmaf(d, d, lsum);
    }

    __shared__ float red[256];
    red[tid] = lsum;
    __syncthreads();
    for (int s = 128; s > 0; s >>= 1) {
        if (tid < s) red[tid] += red[tid + s];
        __syncthreads();
    }
    if (tid == 0) partials[blockIdx.x] = red[0];
}

// Kernel 3: final deterministic reduction of 512 partials -> loss.
__global__ __launch_bounds__(512) void vq_loss_fin(const float* __restrict__ partials,
                                                   float* __restrict__ loss) {
    __shared__ float red[NBLK];
    int t = threadIdx.x;
    red[t] = partials[t];
    __syncthreads();
    for (int s = NBLK / 2; s > 0; s >>= 1) {
        if (t < s) red[t] += red[t + s];
        __syncthreads();
    }
    if (t == 0) loss[0] = red[0] * (1.25f / 8388608.0f);  // (1+BETA)*mean
}

extern "C" void kernel_launch(void* const* d_in, const int* in_sizes, int n_in,
                              void* d_out, int out_size, void* d_ws, size_t ws_size,
                              hipStream_t stream) {
    const float* z_e = (const float*)d_in[0];
    const float* emb = (const float*)d_in[1];

    float* out      = (float*)d_out;
    float* out_q    = out;                       // 8388608 elems
    float* out_idx  = out + 8388608;             // 131072 elems (float-encoded ints)
    float* out_loss = out + 8388608 + 131072;    // 1 elem

    float* E         = (float*)d_ws;                     // 1024 f32
    float* cand_best = E + KCODES;                       // SPLIT*NPTS f32
    int*   cand_k    = (int*)(cand_best + SPLIT * NPTS); // SPLIT*NPTS i32
    float* partials  = (float*)(cand_k + SPLIT * NPTS);  // 512 f32

    vq_esq<<<KCODES / 256, 256, 0, stream>>>(emb, E);
    dim3 grid_scan(NBLK, SPLIT);
    vq_scan<<<grid_scan, 256, 0, stream>>>(z_e, emb, E, cand_best, cand_k);
    vq_merge<<<NBLK, 256, 0, stream>>>(z_e, emb, cand_best, cand_k,
                                       out_q, out_idx, partials);
    vq_loss_fin<<<1, NBLK, 0, stream>>>(partials, out_loss);
}